// Round 12
// baseline (981.260 us; speedup 1.0000x reference)
//
#include <hip/hip_runtime.h>
#include <stdint.h>
#include <stddef.h>

// CharPredictorMultirateFFN on MI355X (gfx950).
// Pipeline: gather(+pad) -> conv_w transpose -> lin_w transpose -> conv GEMM (f16 MFMA)
//           -> linear GEMM + fused softmax.
//
// R18: revert R17's embp-elimination (falsified: conv 801->811, k_lin +15 us from
// scattered tab16 gathers; L3 was already absorbing embp re-reads) -> back to R16
// verbatim (best verified: 960 us), plus exp-once softmax epilogue in k_lin: the sum
// pass stores exp(x-m) back into Ls in place (disjoint 64-elem chunks per thread,
// barrier-separated), final pass is a pure multiply -- removes the second __expf per
// logit (quarter-rate transcendental).
// Ledger: conv 801 us is the structural plateau (MFMA+LDS pipes both ~2/3 across
// R6/R12/R13 schedules; 64x64@3w=833, 128x64@2w=788-801 frontier measured; R7/R11
// finer-phase and R14 32x32-shape all regressed). k_lin M=128 2-phase (R16-verified).

typedef _Float16 f16;
typedef __attribute__((ext_vector_type(8))) _Float16 f16x8;
typedef __attribute__((ext_vector_type(4))) float f32x4;

#define SP 2063  // padded rows per batch item: 15 + 2048

__device__ __forceinline__ void gl2lds16(const void* g, void* l) {
  __builtin_amdgcn_global_load_lds((const __attribute__((address_space(1))) void*)g,
                                   (__attribute__((address_space(3))) void*)l, 16, 0, 0);
}

// ---------------- gather: emb_table[seq] -> f16 padded buffer [32][2063][512] --------
__global__ __launch_bounds__(256) void k_gather(const int* __restrict__ seq,
                                                const float* __restrict__ tab,
                                                f16* __restrict__ embp) {
  int row = blockIdx.x * 4 + (threadIdx.x >> 6);   // 0 .. 66015
  int lane = threadIdx.x & 63;
  int b = row / SP;
  int r = row - b * SP;
  f16* dst = embp + (size_t)row * 512 + lane * 8;
  if (r < 15) {
    f16x8 z = {(f16)0, (f16)0, (f16)0, (f16)0, (f16)0, (f16)0, (f16)0, (f16)0};
    *(f16x8*)dst = z;
  } else {
    int idx = seq[b * 2048 + (r - 15)];
    const float4* src = (const float4*)(tab + (size_t)idx * 512 + lane * 8);
    float4 v0 = src[0], v1 = src[1];
    f16x8 o;
    o[0] = (f16)v0.x; o[1] = (f16)v0.y; o[2] = (f16)v0.z; o[3] = (f16)v0.w;
    o[4] = (f16)v1.x; o[5] = (f16)v1.y; o[6] = (f16)v1.z; o[7] = (f16)v1.w;
    *(f16x8*)dst = o;
  }
}

// ---------------- conv_w [H][E][K] f32 -> wt2 [256 jk][1024 h][32 e5] f16 ------------
// jk = j*16 + k ; e = j*32 + e5. Coalesced read of one h-row into LDS, transpose out.
__global__ __launch_bounds__(256) void k_twc(const float* __restrict__ cw,
                                             f16* __restrict__ wt2) {
  __shared__ f16 tile[8192];          // [e][k] in source order (16 KB)
  int h = blockIdx.x;                 // 1024 blocks
  const float4* src = (const float4*)(cw + (size_t)h * 8192);
#pragma unroll
  for (int i = 0; i < 8; ++i) {
    int o = i * 256 + threadIdx.x;    // float4 index, fully coalesced
    float4 v = src[o];
    f16* d = tile + o * 4;
    d[0] = (f16)v.x; d[1] = (f16)v.y; d[2] = (f16)v.z; d[3] = (f16)v.w;
  }
  __syncthreads();
  // thread t = j*16+k writes 32 halves: wt2[(t*1024 + h)*32 + e5] = tile[(j*32+e5)*16 + k]
  int j = threadIdx.x >> 4, k = threadIdx.x & 15;
  f16* dst = wt2 + ((size_t)threadIdx.x * 1024 + h) * 32;
#pragma unroll
  for (int c8 = 0; c8 < 4; ++c8) {
    f16x8 v;
#pragma unroll
    for (int t = 0; t < 8; ++t) v[t] = tile[((j * 32 + c8 * 8 + t) << 4) | k];
    *(f16x8*)(dst + c8 * 8) = v;
  }
}

// ---------------- lin_w [V][F] f32 -> lt2 [48 fblk][256 v][32] f16 -------------------
__global__ __launch_bounds__(256) void k_twl(const float* __restrict__ lw,
                                             f16* __restrict__ lt2) {
  int o = blockIdx.x * 256 + threadIdx.x;  // 393216 outputs
  int f5 = o & 31;
  int v = (o >> 5) & 255;
  int kb = o >> 13;            // 0..47
  int f = (kb << 5) | f5;
  lt2[o] = (f16)lw[(size_t)v * 1536 + f];
}

// ---------------- conv GEMM: [65536 x 8192] x [8192 x 1024] -> relu -> f16 -----------
// R13 verbatim. 512x64 block, 4 waves stacked in M (each 128x64: acc[8][4], 128
// AGPR). 64 groups of 4 taps: issue B(g+1) into buf (g+1)&1 -> compute 128 MFMA/wave
// -> __syncthreads. A slab (528 rows, 33 KB) single-buffered, restaged per j behind
// a barrier pair. LDS 66.5 KB, 2 blocks/CU.
__global__ __launch_bounds__(256, 2) void k_conv(const f16* __restrict__ embp,
                                                 const f16* __restrict__ wt2,
                                                 const float* __restrict__ cb,
                                                 f16* __restrict__ cout) {
  __shared__ __align__(16) f16 Asl[528 * 32];        // 33 KB A slab (rows 0..526 read)
  __shared__ __align__(16) f16 Bb[2 * 4 * 64 * 32];  // 32 KB: dbuf x 4 taps x 64 rows
  // mb-XCD-pinned swizzle: bid&7 -> XCD; A slab L2-shared by the 16 nb-blocks of the
  // same mb on that XCD.
  int bid = blockIdx.x;                // 2048 blocks
  int x8 = bid & 7;
  int s = bid >> 3;                    // 0..255
  int nb = s & 15;                     // 16 N-blocks of 64
  int mb = ((s >> 4) << 3) | x8;       // 0..127
  int n0 = nb << 6, m0 = mb << 9;      // M block = 512 rows
  int b = m0 >> 11, t0 = m0 & 2047;    // 512 | 2048 -> no item straddle
  int tid = threadIdx.x, lane = tid & 63, wave = tid >> 6;   // wave = M strip 0..3
  int fr = lane & 15, q = lane >> 4;
  int prl = tid >> 2, pc = tid & 3;    // staging: row 0..63 within op, phys chunk

  // A main sources (8 ops cover rows 0..511: op c -> rows c*64 + prl).
  // Source fetches logical chunk pc ^ ((row>>1)&3)  (XOR swizzle; LDS dst linear).
  const f16* gAm[8];
#pragma unroll
  for (int c = 0; c < 8; ++c) {
    int pr = c * 64 + prl;
    int clog = pc ^ ((pr >> 1) & 3);
    gAm[c] = embp + (size_t)(b * SP + t0 + pr) * 512 + clog * 8;
  }
  // A tail rows 512..527: each wave stages the same 1 KB (benign same-data WAW;
  // row 527 staged but never read).
  const f16* gAt;
  {
    int pr = 512 + (lane >> 2);
    int clog = (lane & 3) ^ ((pr >> 1) & 3);
    gAt = embp + (size_t)(b * SP + t0 + pr) * 512 + clog * 8;
  }
  // B source (1 op per tap: rows 0..63 = h cols n0..n0+63), same swizzle.
  const f16* gBm;
  {
    int clog = pc ^ ((prl >> 1) & 3);
    gBm = wt2 + (size_t)(n0 + prl) * 32 + clog * 8;
  }

  int fqB = (q ^ ((fr >> 1) & 3)) << 3;  // B frag phys chunk (rows % 16 aligned)

  f32x4 zero = {0.f, 0.f, 0.f, 0.f};
  f32x4 acc[8][4];
#pragma unroll
  for (int i = 0; i < 8; ++i)
#pragma unroll
    for (int jj = 0; jj < 4; ++jj) acc[i][jj] = zero;

  f16* aD0 = Asl + wave * 512;         // + c*2048 per op
  f16* bD0 = Bb + wave * 512;          // + d*8192 + t*2048

  // prologue: A(j=0) [9 ops], B(group 0) -> buf 0 [4 ops]
#pragma unroll
  for (int c = 0; c < 8; ++c) gl2lds16(gAm[c], aD0 + c * 2048);
  gl2lds16(gAt, Asl + 16384);
#pragma unroll
  for (int t = 0; t < 4; ++t) gl2lds16(gBm + (size_t)t * 32768, bD0 + t * 2048);
  __syncthreads();

#pragma unroll 1
  for (int g = 0; g < 64; ++g) {
    int j = g >> 2;
    // stage NEXT group's 4 B taps into buf (g+1)&1 (read last at group g-1;
    // all waves passed the end-of-(g-1) barrier -> write-safe)
    if (g < 63) {
      const f16* src = gBm + (size_t)(g + 1) * 4 * 32768;
      f16* dst = bD0 + ((g + 1) & 1) * 8192;
#pragma unroll
      for (int t = 0; t < 4; ++t) gl2lds16(src + (size_t)t * 32768, dst + t * 2048);
    }
    // compute group g: taps k = (g&3)*4 .. +3, from Asl and Bb[g&1]
    const f16* Bc = Bb + (g & 1) * 8192;
#pragma unroll
    for (int t = 0; t < 4; ++t) {
      int k = ((g & 3) << 2) + t;
      // A frag: slab row = k + wave*128 + i*16 + fr ; swizzle incl. tap offset k
      // (wave*128 and i*16 are multiples of 8 -> don't affect (row>>1)&3).
      int aswz = ((k + fr) >> 1) & 3;
      const f16* ap = Asl + (size_t)(k + wave * 128 + fr) * 32 + ((q ^ aswz) << 3);
      f16x8 bf[4];
#pragma unroll
      for (int jj = 0; jj < 4; ++jj)
        bf[jj] = *(const f16x8*)(Bc + t * 2048 + (jj * 16 + fr) * 32 + fqB);
#pragma unroll
      for (int i = 0; i < 8; ++i) {
        f16x8 af = *(const f16x8*)(ap + i * 512);
#pragma unroll
        for (int jj = 0; jj < 4; ++jj)
          acc[i][jj] = __builtin_amdgcn_mfma_f32_16x16x32_f16(af, bf[jj], acc[i][jj], 0, 0, 0);
      }
    }
    __syncthreads();   // vmcnt(0): B(g+1) landed (issued one full group ago);
                       // all waves done reading Asl/Bb[g&1].
    // j boundary: restage A for j+1 (A is single-buffered; waves just finished
    // the last taps of j and passed the barrier above)
    if ((g & 3) == 3 && j < 15) {
#pragma unroll
      for (int c = 0; c < 8; ++c) gl2lds16(gAm[c] + (j + 1) * 32, aD0 + c * 2048);
      gl2lds16(gAt + (j + 1) * 32, Asl + 16384);
      __syncthreads();  // drain A(j+1) (L2-warm via mb pinning) before its first read
    }
  }

  // epilogue: bias + relu + f16 store. C/D: col=lane&15 (n), row=(lane>>4)*4+reg (m)
  int col = lane & 15, rq = (lane >> 4) << 2;
  int mbase = m0 + wave * 128 + rq;
  int nbase = n0 + col;
#pragma unroll
  for (int jj = 0; jj < 4; ++jj) {
    int h = nbase + jj * 16;
    float bias = cb[h];
#pragma unroll
    for (int i = 0; i < 8; ++i) {
      int m = mbase + i * 16;
#pragma unroll
      for (int rg = 0; rg < 4; ++rg) {
        float v = acc[i][jj][rg] + bias;
        v = v > 0.f ? v : 0.f;
        cout[(size_t)(m + rg) * 1024 + h] = (f16)v;
      }
    }
  }
}

// ---------------- linear GEMM [65536 x 1536] x [1536 x 256] + fused softmax ----------
// R16: 128x256 block (512 blocks = exactly 2/CU), 4 waves each owning 128x64
// (acc[8][4] = 128 AGPR). 2-phase pipelined: A dbuf 2x8KB + B dbuf 2x16KB = 48 KB;
// stage(kb+1) issued before compute(kb); one __syncthreads per iteration. Epilogue:
// 4 x 32-row softmax halves, Ls [32][261] f32 overlays the staging buffers.
// R18: exp computed ONCE (sum pass stores exp in place; final pass is a multiply).
__global__ __launch_bounds__(256, 2) void k_lin(const f16* __restrict__ embp,
                                                const f16* __restrict__ cout,
                                                const f16* __restrict__ lt2,
                                                const float* __restrict__ lb,
                                                float* __restrict__ out) {
  __shared__ __align__(16) char smem[49152];  // staging dbuf; Ls overlays
  __shared__ float pmax[4][32], psum[4][32], mrow[32], rinv[32];
  f16* As0 = (f16*)smem;              // [2][128][32] 16 KB (buf d at d*4096 f16)
  f16* Bs0 = (f16*)(smem + 16384);    // [2][256][32] 32 KB (buf d at d*8192 f16)
  float* Ls = (float*)smem;           // [32][261] f32 epilogue logits (33.4 KB)
  int m0 = blockIdx.x << 7;           // 512 blocks x 128 rows
  int b = m0 >> 11, t0 = m0 & 2047;   // 128 | 2048 -> no item straddle
  int tid = threadIdx.x, lane = tid & 63, wave = tid >> 6;
  int sr = lane >> 2, sc = (lane & 3) << 3;
  // A sources: op c (c=0,1) covers rows wave*16 + c*64 + sr (16 rows/wave/op)
  const f16* gAe[2];
  const f16* gAc[2];
#pragma unroll
  for (int c = 0; c < 2; ++c) {
    int r = wave * 16 + c * 64 + sr;
    gAe[c] = embp + (size_t)(b * SP + 15 + t0 + r) * 512 + sc;
    gAc[c] = cout + (size_t)(m0 + r) * 1024 + sc;
  }
  int fr = lane & 15, fq = (lane >> 4) << 3;
  f32x4 zero = {0.f, 0.f, 0.f, 0.f};
  f32x4 acc[8][4];
#pragma unroll
  for (int i = 0; i < 8; ++i)
#pragma unroll
    for (int j = 0; j < 4; ++j) acc[i][j] = zero;

  // stage K-block kb into buffer kb&1 (6 gl2lds per wave: 2 A + 4 B)
  auto stage = [&](int kb) {
    f16* lA = As0 + (kb & 1) * 4096 + wave * 512;
    if (kb < 16) {
#pragma unroll
      for (int c = 0; c < 2; ++c) gl2lds16(gAe[c] + kb * 32, lA + c * 2048);
    } else {
#pragma unroll
      for (int c = 0; c < 2; ++c) gl2lds16(gAc[c] + (kb - 16) * 32, lA + c * 2048);
    }
    f16* lB = Bs0 + (kb & 1) * 8192;
#pragma unroll
    for (int jj = 0; jj < 4; ++jj) {
      int c = wave * 4 + jj;
      gl2lds16(lt2 + (size_t)kb * 8192 + (c * 16 + sr) * 32 + sc, lB + c * 512);
    }
  };

  stage(0);
  __syncthreads();               // stage(0) landed

#pragma unroll 1
  for (int kb = 0; kb < 48; ++kb) {
    if (kb < 47) stage(kb + 1);  // overlaps with compute(kb)
    const f16* As = As0 + (kb & 1) * 4096;
    const f16* Bs = Bs0 + (kb & 1) * 8192;
    f16x8 bf[4];
#pragma unroll
    for (int j = 0; j < 4; ++j)
      bf[j] = *(const f16x8*)(Bs + (wave * 64 + j * 16 + fr) * 32 + fq);
#pragma unroll
    for (int i = 0; i < 8; ++i) {
      f16x8 af = *(const f16x8*)(As + (i * 16 + fr) * 32 + fq);
#pragma unroll
      for (int j = 0; j < 4; ++j)
        acc[i][j] = __builtin_amdgcn_mfma_f32_16x16x32_f16(af, bf[j], acc[i][j], 0, 0, 0);
    }
    __syncthreads();             // drains stage(kb+1); releases buf kb&1
  }

  // softmax epilogue, four 32-row halves. Ls stride 261 (coprime with 32).
  int col = lane & 15, rq = (lane >> 4) << 2;
  for (int hf = 0; hf < 4; ++hf) {
    __syncthreads();
#pragma unroll
    for (int j = 0; j < 4; ++j) {
      int v = wave * 64 + j * 16 + col;
      float bias = lb[v];
#pragma unroll
      for (int i2 = 0; i2 < 2; ++i2) {
        int rloc = i2 * 16 + rq;
        int ig = hf * 2 + i2;
#pragma unroll
        for (int rg = 0; rg < 4; ++rg)
          Ls[(rloc + rg) * 261 + v] = acc[ig][j][rg] + bias;
      }
    }
    __syncthreads();
    if (tid < 128) {
      int r = tid & 31, qd = tid >> 5;
      const float* rowp = Ls + r * 261 + qd * 64;
      float pm = -1e30f;
#pragma unroll 8
      for (int c = 0; c < 64; ++c) pm = fmaxf(pm, rowp[c]);
      pmax[qd][r] = pm;
    }
    __syncthreads();
    if (tid < 32)
      mrow[tid] = fmaxf(fmaxf(pmax[0][tid], pmax[1][tid]), fmaxf(pmax[2][tid], pmax[3][tid]));
    __syncthreads();
    if (tid < 128) {
      int r = tid & 31, qd = tid >> 5;
      float* rowp = Ls + r * 261 + qd * 64;
      float mr = mrow[r], ps = 0.f;
#pragma unroll 8
      for (int c = 0; c < 64; ++c) {
        float e = __expf(rowp[c] - mr);
        rowp[c] = e;               // exp-once: store back in place
        ps += e;
      }
      psum[qd][r] = ps;
    }
    __syncthreads();
    if (tid < 32)
      rinv[tid] = 1.f / (psum[0][tid] + psum[1][tid] + psum[2][tid] + psum[3][tid]);
    __syncthreads();
    float* obase = out + (size_t)(m0 + hf * 32) * 256 + tid;
#pragma unroll 4
    for (int r = 0; r < 32; ++r)
      obase[(size_t)r * 256] = Ls[r * 261 + tid] * rinv[r];
  }
}

extern "C" void kernel_launch(void* const* d_in, const int* in_sizes, int n_in,
                              void* d_out, int out_size, void* d_ws, size_t ws_size,
                              hipStream_t stream) {
  const int*   seq = (const int*)d_in[0];
  const float* tab = (const float*)d_in[1];
  const float* cw  = (const float*)d_in[2];
  const float* cb  = (const float*)d_in[3];
  const float* lw  = (const float*)d_in[4];
  const float* lb  = (const float*)d_in[5];
  float* out = (float*)d_out;
  char* ws = (char*)d_ws;
  // workspace layout (needs ~219.4 MB):
  f16* embp = (f16*)(ws);               //  67,600,384 B  [32*2063][512]
  f16* cout = (f16*)(ws + 67600384);    // 134,217,728 B  [65536][1024]
  f16* wt2  = (f16*)(ws + 201818112);   //  16,777,216 B  [256 jk][1024 h][32 e5]
  f16* lt2  = (f16*)(ws + 218595328);   //     786,432 B  [48][256][32]

  hipLaunchKernelGGL(k_gather, dim3(16504), dim3(256), 0, stream, seq, tab, embp);
  hipLaunchKernelGGL(k_twc,    dim3(1024),  dim3(256), 0, stream, cw, wt2);
  hipLaunchKernelGGL(k_twl,    dim3(1536),  dim3(256), 0, stream, lw, lt2);
  hipLaunchKernelGGL(k_conv,   dim3(2048),  dim3(256), 0, stream, embp, wt2, cb, cout);
  hipLaunchKernelGGL(k_lin,    dim3(512),   dim3(256), 0, stream, embp, cout, lt2, lb, out);
}

// Round 13
// 959.901 us; speedup vs baseline: 1.0223x; 1.0223x over previous
//
#include <hip/hip_runtime.h>
#include <stdint.h>
#include <stddef.h>

// CharPredictorMultirateFFN on MI355X (gfx950).
// Pipeline: prep (fused gather + conv_w transpose + lin_w transpose, one launch)
//           -> conv GEMM (f16 MFMA) -> linear GEMM + fused softmax.
//
// R19: R16 verbatim (verified best: 960 us; R18's exp-once coincided with +21 us and
// is reverted per rigor rules) + the three independent prep kernels merged into one
// grid-partitioned launch: blocks [0,16504) gather, [16504,17528) twc, [17528,19064)
// twl. Removes two dispatch boundaries and overlaps twc/twl under gather's BW-bound
// tail (sum -> max). Bodies byte-identical to R16's kernels.
// Ledger: conv 800-810 us / MfmaUtil ~67 is the structural plateau across all tried
// structures (R6/R7/R11/R12 schedules, R10/R13 tiles, R14 shape, R8/R9/R17 dataflow).

typedef _Float16 f16;
typedef __attribute__((ext_vector_type(8))) _Float16 f16x8;
typedef __attribute__((ext_vector_type(4))) float f32x4;

#define SP 2063  // padded rows per batch item: 15 + 2048

__device__ __forceinline__ void gl2lds16(const void* g, void* l) {
  __builtin_amdgcn_global_load_lds((const __attribute__((address_space(1))) void*)g,
                                   (__attribute__((address_space(3))) void*)l, 16, 0, 0);
}

// ---------------- fused prep: gather | conv_w transpose | lin_w transpose -----------
// gather: emb_table[seq] -> f16 padded buffer [32][2063][512]
// twc:    conv_w [H][E][K] f32 -> wt2 [256 jk][1024 h][32 e5] f16
// twl:    lin_w [V][F] f32 -> lt2 [48 fblk][256 v][32] f16
__global__ __launch_bounds__(256) void k_prep(const int* __restrict__ seq,
                                              const float* __restrict__ tab,
                                              f16* __restrict__ embp,
                                              const float* __restrict__ cw,
                                              f16* __restrict__ wt2,
                                              const float* __restrict__ lw,
                                              f16* __restrict__ lt2) {
  __shared__ f16 tile[8192];          // used by twc partition only (16 KB)
  int bid = blockIdx.x;
  if (bid < 16504) {
    // ---- gather ----
    int row = bid * 4 + (threadIdx.x >> 6);        // 0 .. 66015
    int lane = threadIdx.x & 63;
    int b = row / SP;
    int r = row - b * SP;
    f16* dst = embp + (size_t)row * 512 + lane * 8;
    if (r < 15) {
      f16x8 z = {(f16)0, (f16)0, (f16)0, (f16)0, (f16)0, (f16)0, (f16)0, (f16)0};
      *(f16x8*)dst = z;
    } else {
      int idx = seq[b * 2048 + (r - 15)];
      const float4* src = (const float4*)(tab + (size_t)idx * 512 + lane * 8);
      float4 v0 = src[0], v1 = src[1];
      f16x8 o;
      o[0] = (f16)v0.x; o[1] = (f16)v0.y; o[2] = (f16)v0.z; o[3] = (f16)v0.w;
      o[4] = (f16)v1.x; o[5] = (f16)v1.y; o[6] = (f16)v1.z; o[7] = (f16)v1.w;
      *(f16x8*)dst = o;
    }
  } else if (bid < 16504 + 1024) {
    // ---- twc ----
    int h = bid - 16504;               // 0..1023
    const float4* src = (const float4*)(cw + (size_t)h * 8192);
#pragma unroll
    for (int i = 0; i < 8; ++i) {
      int o = i * 256 + threadIdx.x;   // float4 index, fully coalesced
      float4 v = src[o];
      f16* d = tile + o * 4;
      d[0] = (f16)v.x; d[1] = (f16)v.y; d[2] = (f16)v.z; d[3] = (f16)v.w;
    }
    __syncthreads();
    // thread t = j*16+k writes 32 halves: wt2[(t*1024+h)*32 + e5] = tile[(j*32+e5)*16 + k]
    int j = threadIdx.x >> 4, k = threadIdx.x & 15;
    f16* dst = wt2 + ((size_t)threadIdx.x * 1024 + h) * 32;
#pragma unroll
    for (int c8 = 0; c8 < 4; ++c8) {
      f16x8 v;
#pragma unroll
      for (int t = 0; t < 8; ++t) v[t] = tile[((j * 32 + c8 * 8 + t) << 4) | k];
      *(f16x8*)(dst + c8 * 8) = v;
    }
  } else {
    // ---- twl ----
    int o = (bid - 17528) * 256 + threadIdx.x;  // 393216 outputs
    int f5 = o & 31;
    int v = (o >> 5) & 255;
    int kb = o >> 13;            // 0..47
    int f = (kb << 5) | f5;
    lt2[o] = (f16)lw[(size_t)v * 1536 + f];
  }
}

// ---------------- conv GEMM: [65536 x 8192] x [8192 x 1024] -> relu -> f16 -----------
// R13 verbatim. 512x64 block, 4 waves stacked in M (each 128x64: acc[8][4], 128
// AGPR). 64 groups of 4 taps: issue B(g+1) into buf (g+1)&1 -> compute 128 MFMA/wave
// -> __syncthreads. A slab (528 rows, 33 KB) single-buffered, restaged per j behind
// a barrier pair. LDS 66.5 KB, 2 blocks/CU.
__global__ __launch_bounds__(256, 2) void k_conv(const f16* __restrict__ embp,
                                                 const f16* __restrict__ wt2,
                                                 const float* __restrict__ cb,
                                                 f16* __restrict__ cout) {
  __shared__ __align__(16) f16 Asl[528 * 32];        // 33 KB A slab (rows 0..526 read)
  __shared__ __align__(16) f16 Bb[2 * 4 * 64 * 32];  // 32 KB: dbuf x 4 taps x 64 rows
  // mb-XCD-pinned swizzle: bid&7 -> XCD; A slab L2-shared by the 16 nb-blocks of the
  // same mb on that XCD.
  int bid = blockIdx.x;                // 2048 blocks
  int x8 = bid & 7;
  int s = bid >> 3;                    // 0..255
  int nb = s & 15;                     // 16 N-blocks of 64
  int mb = ((s >> 4) << 3) | x8;       // 0..127
  int n0 = nb << 6, m0 = mb << 9;      // M block = 512 rows
  int b = m0 >> 11, t0 = m0 & 2047;    // 512 | 2048 -> no item straddle
  int tid = threadIdx.x, lane = tid & 63, wave = tid >> 6;   // wave = M strip 0..3
  int fr = lane & 15, q = lane >> 4;
  int prl = tid >> 2, pc = tid & 3;    // staging: row 0..63 within op, phys chunk

  // A main sources (8 ops cover rows 0..511: op c -> rows c*64 + prl).
  // Source fetches logical chunk pc ^ ((row>>1)&3)  (XOR swizzle; LDS dst linear).
  const f16* gAm[8];
#pragma unroll
  for (int c = 0; c < 8; ++c) {
    int pr = c * 64 + prl;
    int clog = pc ^ ((pr >> 1) & 3);
    gAm[c] = embp + (size_t)(b * SP + t0 + pr) * 512 + clog * 8;
  }
  // A tail rows 512..527: each wave stages the same 1 KB (benign same-data WAW;
  // row 527 staged but never read).
  const f16* gAt;
  {
    int pr = 512 + (lane >> 2);
    int clog = (lane & 3) ^ ((pr >> 1) & 3);
    gAt = embp + (size_t)(b * SP + t0 + pr) * 512 + clog * 8;
  }
  // B source (1 op per tap: rows 0..63 = h cols n0..n0+63), same swizzle.
  const f16* gBm;
  {
    int clog = pc ^ ((prl >> 1) & 3);
    gBm = wt2 + (size_t)(n0 + prl) * 32 + clog * 8;
  }

  int fqB = (q ^ ((fr >> 1) & 3)) << 3;  // B frag phys chunk (rows % 16 aligned)

  f32x4 zero = {0.f, 0.f, 0.f, 0.f};
  f32x4 acc[8][4];
#pragma unroll
  for (int i = 0; i < 8; ++i)
#pragma unroll
    for (int jj = 0; jj < 4; ++jj) acc[i][jj] = zero;

  f16* aD0 = Asl + wave * 512;         // + c*2048 per op
  f16* bD0 = Bb + wave * 512;          // + d*8192 + t*2048

  // prologue: A(j=0) [9 ops], B(group 0) -> buf 0 [4 ops]
#pragma unroll
  for (int c = 0; c < 8; ++c) gl2lds16(gAm[c], aD0 + c * 2048);
  gl2lds16(gAt, Asl + 16384);
#pragma unroll
  for (int t = 0; t < 4; ++t) gl2lds16(gBm + (size_t)t * 32768, bD0 + t * 2048);
  __syncthreads();

#pragma unroll 1
  for (int g = 0; g < 64; ++g) {
    int j = g >> 2;
    // stage NEXT group's 4 B taps into buf (g+1)&1 (read last at group g-1;
    // all waves passed the end-of-(g-1) barrier -> write-safe)
    if (g < 63) {
      const f16* src = gBm + (size_t)(g + 1) * 4 * 32768;
      f16* dst = bD0 + ((g + 1) & 1) * 8192;
#pragma unroll
      for (int t = 0; t < 4; ++t) gl2lds16(src + (size_t)t * 32768, dst + t * 2048);
    }
    // compute group g: taps k = (g&3)*4 .. +3, from Asl and Bb[g&1]
    const f16* Bc = Bb + (g & 1) * 8192;
#pragma unroll
    for (int t = 0; t < 4; ++t) {
      int k = ((g & 3) << 2) + t;
      // A frag: slab row = k + wave*128 + i*16 + fr ; swizzle incl. tap offset k
      // (wave*128 and i*16 are multiples of 8 -> don't affect (row>>1)&3).
      int aswz = ((k + fr) >> 1) & 3;
      const f16* ap = Asl + (size_t)(k + wave * 128 + fr) * 32 + ((q ^ aswz) << 3);
      f16x8 bf[4];
#pragma unroll
      for (int jj = 0; jj < 4; ++jj)
        bf[jj] = *(const f16x8*)(Bc + t * 2048 + (jj * 16 + fr) * 32 + fqB);
#pragma unroll
      for (int i = 0; i < 8; ++i) {
        f16x8 af = *(const f16x8*)(ap + i * 512);
#pragma unroll
        for (int jj = 0; jj < 4; ++jj)
          acc[i][jj] = __builtin_amdgcn_mfma_f32_16x16x32_f16(af, bf[jj], acc[i][jj], 0, 0, 0);
      }
    }
    __syncthreads();   // vmcnt(0): B(g+1) landed (issued one full group ago);
                       // all waves done reading Asl/Bb[g&1].
    // j boundary: restage A for j+1 (A is single-buffered; waves just finished
    // the last taps of j and passed the barrier above)
    if ((g & 3) == 3 && j < 15) {
#pragma unroll
      for (int c = 0; c < 8; ++c) gl2lds16(gAm[c] + (j + 1) * 32, aD0 + c * 2048);
      gl2lds16(gAt + (j + 1) * 32, Asl + 16384);
      __syncthreads();  // drain A(j+1) (L2-warm via mb pinning) before its first read
    }
  }

  // epilogue: bias + relu + f16 store. C/D: col=lane&15 (n), row=(lane>>4)*4+reg (m)
  int col = lane & 15, rq = (lane >> 4) << 2;
  int mbase = m0 + wave * 128 + rq;
  int nbase = n0 + col;
#pragma unroll
  for (int jj = 0; jj < 4; ++jj) {
    int h = nbase + jj * 16;
    float bias = cb[h];
#pragma unroll
    for (int i = 0; i < 8; ++i) {
      int m = mbase + i * 16;
#pragma unroll
      for (int rg = 0; rg < 4; ++rg) {
        float v = acc[i][jj][rg] + bias;
        v = v > 0.f ? v : 0.f;
        cout[(size_t)(m + rg) * 1024 + h] = (f16)v;
      }
    }
  }
}

// ---------------- linear GEMM [65536 x 1536] x [1536 x 256] + fused softmax ----------
// R16 verbatim: 128x256 block (512 blocks = exactly 2/CU), 4 waves each owning
// 128x64 (acc[8][4] = 128 AGPR). 2-phase pipelined: A dbuf 2x8KB + B dbuf 2x16KB =
// 48 KB; stage(kb+1) issued before compute(kb); one __syncthreads per iteration.
// Epilogue: 4 x 32-row softmax halves, Ls [32][261] f32 overlays staging buffers.
__global__ __launch_bounds__(256, 2) void k_lin(const f16* __restrict__ embp,
                                                const f16* __restrict__ cout,
                                                const f16* __restrict__ lt2,
                                                const float* __restrict__ lb,
                                                float* __restrict__ out) {
  __shared__ __align__(16) char smem[49152];  // staging dbuf; Ls overlays
  __shared__ float pmax[4][32], psum[4][32], mrow[32], rinv[32];
  f16* As0 = (f16*)smem;              // [2][128][32] 16 KB (buf d at d*4096 f16)
  f16* Bs0 = (f16*)(smem + 16384);    // [2][256][32] 32 KB (buf d at d*8192 f16)
  float* Ls = (float*)smem;           // [32][261] f32 epilogue logits (33.4 KB)
  int m0 = blockIdx.x << 7;           // 512 blocks x 128 rows
  int b = m0 >> 11, t0 = m0 & 2047;   // 128 | 2048 -> no item straddle
  int tid = threadIdx.x, lane = tid & 63, wave = tid >> 6;
  int sr = lane >> 2, sc = (lane & 3) << 3;
  // A sources: op c (c=0,1) covers rows wave*16 + c*64 + sr (16 rows/wave/op)
  const f16* gAe[2];
  const f16* gAc[2];
#pragma unroll
  for (int c = 0; c < 2; ++c) {
    int r = wave * 16 + c * 64 + sr;
    gAe[c] = embp + (size_t)(b * SP + 15 + t0 + r) * 512 + sc;
    gAc[c] = cout + (size_t)(m0 + r) * 1024 + sc;
  }
  int fr = lane & 15, fq = (lane >> 4) << 3;
  f32x4 zero = {0.f, 0.f, 0.f, 0.f};
  f32x4 acc[8][4];
#pragma unroll
  for (int i = 0; i < 8; ++i)
#pragma unroll
    for (int j = 0; j < 4; ++j) acc[i][j] = zero;

  // stage K-block kb into buffer kb&1 (6 gl2lds per wave: 2 A + 4 B)
  auto stage = [&](int kb) {
    f16* lA = As0 + (kb & 1) * 4096 + wave * 512;
    if (kb < 16) {
#pragma unroll
      for (int c = 0; c < 2; ++c) gl2lds16(gAe[c] + kb * 32, lA + c * 2048);
    } else {
#pragma unroll
      for (int c = 0; c < 2; ++c) gl2lds16(gAc[c] + (kb - 16) * 32, lA + c * 2048);
    }
    f16* lB = Bs0 + (kb & 1) * 8192;
#pragma unroll
    for (int jj = 0; jj < 4; ++jj) {
      int c = wave * 4 + jj;
      gl2lds16(lt2 + (size_t)kb * 8192 + (c * 16 + sr) * 32 + sc, lB + c * 512);
    }
  };

  stage(0);
  __syncthreads();               // stage(0) landed

#pragma unroll 1
  for (int kb = 0; kb < 48; ++kb) {
    if (kb < 47) stage(kb + 1);  // overlaps with compute(kb)
    const f16* As = As0 + (kb & 1) * 4096;
    const f16* Bs = Bs0 + (kb & 1) * 8192;
    f16x8 bf[4];
#pragma unroll
    for (int j = 0; j < 4; ++j)
      bf[j] = *(const f16x8*)(Bs + (wave * 64 + j * 16 + fr) * 32 + fq);
#pragma unroll
    for (int i = 0; i < 8; ++i) {
      f16x8 af = *(const f16x8*)(As + (i * 16 + fr) * 32 + fq);
#pragma unroll
      for (int j = 0; j < 4; ++j)
        acc[i][j] = __builtin_amdgcn_mfma_f32_16x16x32_f16(af, bf[j], acc[i][j], 0, 0, 0);
    }
    __syncthreads();             // drains stage(kb+1); releases buf kb&1
  }

  // softmax epilogue, four 32-row halves. Ls stride 261 (coprime with 32).
  int col = lane & 15, rq = (lane >> 4) << 2;
  for (int hf = 0; hf < 4; ++hf) {
    __syncthreads();
#pragma unroll
    for (int j = 0; j < 4; ++j) {
      int v = wave * 64 + j * 16 + col;
      float bias = lb[v];
#pragma unroll
      for (int i2 = 0; i2 < 2; ++i2) {
        int rloc = i2 * 16 + rq;
        int ig = hf * 2 + i2;
#pragma unroll
        for (int rg = 0; rg < 4; ++rg)
          Ls[(rloc + rg) * 261 + v] = acc[ig][j][rg] + bias;
      }
    }
    __syncthreads();
    if (tid < 128) {
      int r = tid & 31, qd = tid >> 5;
      const float* rowp = Ls + r * 261 + qd * 64;
      float pm = -1e30f;
#pragma unroll 8
      for (int c = 0; c < 64; ++c) pm = fmaxf(pm, rowp[c]);
      pmax[qd][r] = pm;
    }
    __syncthreads();
    if (tid < 32)
      mrow[tid] = fmaxf(fmaxf(pmax[0][tid], pmax[1][tid]), fmaxf(pmax[2][tid], pmax[3][tid]));
    __syncthreads();
    if (tid < 128) {
      int r = tid & 31, qd = tid >> 5;
      const float* rowp = Ls + r * 261 + qd * 64;
      float mr = mrow[r], ps = 0.f;
#pragma unroll 8
      for (int c = 0; c < 64; ++c) ps += __expf(rowp[c] - mr);
      psum[qd][r] = ps;
    }
    __syncthreads();
    if (tid < 32)
      rinv[tid] = 1.f / (psum[0][tid] + psum[1][tid] + psum[2][tid] + psum[3][tid]);
    __syncthreads();
    float* obase = out + (size_t)(m0 + hf * 32) * 256 + tid;
#pragma unroll 4
    for (int r = 0; r < 32; ++r)
      obase[(size_t)r * 256] = __expf(Ls[r * 261 + tid] - mrow[r]) * rinv[r];
  }
}

extern "C" void kernel_launch(void* const* d_in, const int* in_sizes, int n_in,
                              void* d_out, int out_size, void* d_ws, size_t ws_size,
                              hipStream_t stream) {
  const int*   seq = (const int*)d_in[0];
  const float* tab = (const float*)d_in[1];
  const float* cw  = (const float*)d_in[2];
  const float* cb  = (const float*)d_in[3];
  const float* lw  = (const float*)d_in[4];
  const float* lb  = (const float*)d_in[5];
  float* out = (float*)d_out;
  char* ws = (char*)d_ws;
  // workspace layout (needs ~219.4 MB):
  f16* embp = (f16*)(ws);               //  67,600,384 B  [32*2063][512]
  f16* cout = (f16*)(ws + 67600384);    // 134,217,728 B  [65536][1024]
  f16* wt2  = (f16*)(ws + 201818112);   //  16,777,216 B  [256 jk][1024 h][32 e5]
  f16* lt2  = (f16*)(ws + 218595328);   //     786,432 B  [48][256][32]

  hipLaunchKernelGGL(k_prep, dim3(19064), dim3(256), 0, stream,
                     seq, tab, embp, cw, wt2, lw, lt2);
  hipLaunchKernelGGL(k_conv, dim3(2048), dim3(256), 0, stream, embp, wt2, cb, cout);
  hipLaunchKernelGGL(k_lin,  dim3(512),  dim3(256), 0, stream, embp, cout, lt2, lb, out);
}